// Round 1
// baseline (50.075 us; speedup 1.0000x reference)
//
#include <hip/hip_runtime.h>
#include <math.h>

#define NEG_INF (-1.0e9f)
#define EPSF (1e-8f)

__device__ __forceinline__ float n2n(float x) {
    // nan_to_num(nan=0, posinf=0, neginf=0)
    return isfinite(x) ? x : 0.0f;
}

__device__ __forceinline__ float tanh_fast(float x) {
    // tanh via exp; clamp so exp never overflows (exp(40) ~ 2.4e17, safe)
    float xc = fminf(fmaxf(x, -20.0f), 20.0f);
    float t = __expf(2.0f * xc);
    return (t - 1.0f) / (t + 1.0f);
}

// One block per batch row b. 256 threads = 4 waves. N=1024, F=8.
// Each thread handles 4 n positions (tid, tid+256, tid+512, tid+768),
// loading X[b,n,0:8] as two float4 (32B contiguous per element).
__global__ __launch_bounds__(256) void setdsr_kernel(
    const float* __restrict__ X, const float* __restrict__ mask,
    float* __restrict__ out)
{
    const int b = blockIdx.x;
    const int tid = threadIdx.x;
    const int N = 1024;

    const float4* __restrict__ Xr =
        reinterpret_cast<const float4*>(X + (size_t)b * N * 8);
    const float* __restrict__ Mr = mask + (size_t)b * N;

    float s1 = 0.f;          // sum((x0*x1)^2 * m)
    float s2 = 0.f;          // sum((safelog(x2)+tanh(x3)) * m)
    float sm = 0.f;          // sum(m)
    float svw = 0.f;         // sum(v*w)
    float sw = 0.f;          // sum(w)
    float mx5 = NEG_INF;     // max(sin(x0)*cos(x1) masked)
    float e3[4];             // lse scores (x4-x5 masked)

    #pragma unroll
    for (int k = 0; k < 4; ++k) {
        int n = tid + k * 256;
        float mk = Mr[n];
        float4 lo = Xr[2 * n];
        float4 hi = Xr[2 * n + 1];
        float x0 = lo.x, x1 = lo.y, x2 = lo.z, x3 = lo.w;
        float x4 = hi.x, x5 = hi.y, x6 = hi.z, x7 = hi.w;

        float p = x0 * x1;
        s1 += p * p * mk;

        float t2e = __logf(fabsf(x2) + EPSF) + tanh_fast(x3);
        s2 += t2e * mk;
        sm += mk;

        e3[k] = (mk > 0.f) ? (x4 - x5) : NEG_INF;

        float w = n2n(fabsf(x7)) * mk;
        float v = n2n(x6);
        svw += v * w;
        sw += w;

        float t5e = __sinf(x0) * __cosf(x1);
        mx5 = fmaxf(mx5, (mk > 0.f) ? t5e : NEG_INF);
    }

    // Per-thread deferred LSE over the 4 register-held scores.
    float m3 = fmaxf(fmaxf(e3[0], e3[1]), fmaxf(e3[2], e3[3]));
    float s3 = __expf(e3[0] - m3) + __expf(e3[1] - m3) +
               __expf(e3[2] - m3) + __expf(e3[3] - m3);

    // Wave-64 butterfly reduction (all 8 partials).
    #pragma unroll
    for (int off = 32; off > 0; off >>= 1) {
        s1  += __shfl_xor(s1, off);
        s2  += __shfl_xor(s2, off);
        sm  += __shfl_xor(sm, off);
        svw += __shfl_xor(svw, off);
        sw  += __shfl_xor(sw, off);
        mx5 = fmaxf(mx5, __shfl_xor(mx5, off));
        float m3o = __shfl_xor(m3, off);
        float s3o = __shfl_xor(s3, off);
        float M = fmaxf(m3, m3o);
        s3 = s3 * __expf(m3 - M) + s3o * __expf(m3o - M);
        m3 = M;
    }

    // Cross-wave merge via tiny LDS (4 waves x 8 partials).
    __shared__ float red[4][8];
    int wave = tid >> 6;
    if ((tid & 63) == 0) {
        red[wave][0] = s1;  red[wave][1] = s2;  red[wave][2] = sm;
        red[wave][3] = svw; red[wave][4] = sw;  red[wave][5] = mx5;
        red[wave][6] = m3;  red[wave][7] = s3;
    }
    __syncthreads();
    if (tid == 0) {
        float S1 = red[0][0], S2 = red[0][1], SM = red[0][2];
        float SVW = red[0][3], SW = red[0][4], MX = red[0][5];
        float M3 = red[0][6], S3 = red[0][7];
        #pragma unroll
        for (int w2 = 1; w2 < 4; ++w2) {
            S1  += red[w2][0];
            S2  += red[w2][1];
            SM  += red[w2][2];
            SVW += red[w2][3];
            SW  += red[w2][4];
            MX = fmaxf(MX, red[w2][5]);
            float m2 = red[w2][6], sx = red[w2][7];
            float M = fmaxf(M3, m2);
            S3 = S3 * __expf(M3 - M) + sx * __expf(m2 - M);
            M3 = M;
        }
        float t1 = S1;
        float t2 = S2 / (SM + EPSF);
        float t3 = __logf(S3) + M3;
        float t4 = SVW / (SW + EPSF);
        float t5 = MX;
        out[b] = t1 + t2 + t3 + t4 + t5;
    }
}

extern "C" void kernel_launch(void* const* d_in, const int* in_sizes, int n_in,
                              void* d_out, int out_size, void* d_ws, size_t ws_size,
                              hipStream_t stream) {
    const float* X = (const float*)d_in[0];       // (8192, 1024, 8) f32
    const float* mask = (const float*)d_in[1];    // (8192, 1024) f32
    float* out = (float*)d_out;                   // (8192,) f32
    int B = out_size;                             // 8192
    setdsr_kernel<<<B, 256, 0, stream>>>(X, mask, out);
}